// Round 10
// baseline (255.659 us; speedup 1.0000x reference)
//
#include <hip/hip_runtime.h>

#define N_NODES 20000
#define N_EDGES 200000
#define HID 128
#define STR 136   // LDS row stride in u16: 272B rows -> every b128 access 16B-aligned
#define NBLK 3125 // 64-edge tiles
#define NPRE 313  // 64-node tiles for dense node GEMMs (313*64 = 20032)
#define NREP 64   // BN accumulator replicas

typedef unsigned short u16;
using bf16x8 = __attribute__((ext_vector_type(8))) __bf16;
using f32x4  = __attribute__((ext_vector_type(4))) float;

__device__ __forceinline__ u16 f2bf(float f) {
  union { float f; unsigned u; } v; v.f = f;
  unsigned u = v.u;
  return (u16)((u + 0x7FFFu + ((u >> 16) & 1u)) >> 16);
}
__device__ __forceinline__ float bf2f(unsigned s) {
  union { unsigned u; float f; } v; v.u = s << 16;
  return v.f;
}
__device__ __forceinline__ bf16x8 ld8(const u16* p) { return *(const bf16x8*)p; }

__device__ __forceinline__ void zero_acc8(f32x4 acc[4]) {
#pragma unroll
  for (int i = 0; i < 4; ++i) acc[i] = (f32x4){0.f, 0.f, 0.f, 0.f};
}

// r4-proven: depth-1 B prefetch, 8-wave, wave w owns cols w*16..w*16+15.
template <int KSTEPS, typename AF>
__device__ __forceinline__ void wgemm8(const u16* __restrict__ PW, AF afrag,
                                       f32x4 acc[4], int lane, int wave) {
  const u16* pb = PW + (wave * 64 + lane) * 8;
  bf16x8 b[2];
  b[0] = ld8(pb);
#pragma unroll
  for (int ks = 0; ks < KSTEPS; ++ks) {
    const int cur = ks & 1;
    if (ks + 1 < KSTEPS) b[cur ^ 1] = ld8(pb + (ks + 1) * 4096);
#pragma unroll
    for (int mt = 0; mt < 4; ++mt) {
      bf16x8 a = afrag(ks, mt);
      acc[mt] = __builtin_amdgcn_mfma_f32_16x16x32_bf16(a, b[cur], acc[mt], 0, 0, 0);
    }
  }
}

// C/D: row(edge) = mt*16 + (lane>>4)*4 + r, col(ch) = wave*16 + (lane&15).
template <bool RELU>
__device__ __forceinline__ void epi_store8(u16* buf, const f32x4 acc[4],
                                           const float* __restrict__ bias,
                                           int lane, int wave) {
  const int c = lane & 15, q = lane >> 4;
  const float bb = bias[wave * 16 + c];
  const int col = wave * 16 + c;
#pragma unroll
  for (int mt = 0; mt < 4; ++mt)
#pragma unroll
    for (int r = 0; r < 4; ++r) {
      float v = acc[mt][r] + bb;
      if (RELU) v = fmaxf(v, 0.f);
      buf[(mt * 16 + q * 4 + r) * STR + col] = f2bf(v);
    }
}

// acc + LDS-add-term (+bias) -> relu -> out. Used for the factored node terms.
template <bool RELU>
__device__ __forceinline__ void epi_add8(u16* out, const u16* addb,
                                         const f32x4 acc[4],
                                         const float* __restrict__ bias,
                                         int lane, int wave) {
  const int c = lane & 15, q = lane >> 4;
  const int col = wave * 16 + c;
  const float bb = bias[col];
#pragma unroll
  for (int mt = 0; mt < 4; ++mt)
#pragma unroll
    for (int r = 0; r < 4; ++r) {
      int row = mt * 16 + q * 4 + r;
      float v = acc[mt][r] + bf2f(addb[row * STR + col]) + bb;
      if (RELU) v = fmaxf(v, 0.f);
      out[row * STR + col] = f2bf(v);
    }
}

__device__ __forceinline__ void epi_plain8(u16* buf, const f32x4 acc[4],
                                           int lane, int wave) {
  const int c = lane & 15, q = lane >> 4;
  const int col = wave * 16 + c;
#pragma unroll
  for (int mt = 0; mt < 4; ++mt)
#pragma unroll
    for (int r = 0; r < 4; ++r)
      buf[(mt * 16 + q * 4 + r) * STR + col] = f2bf(acc[mt][r]);
}

__device__ __forceinline__ void flush_buf8(const u16* buf, u16* __restrict__ gout,
                                           int e0, int tid) {
#pragma unroll
  for (int it = 0; it < 2; ++it) {
    int cid = tid + it * 512, e = cid >> 4, p = cid & 15;
    uint4 v = *(const uint4*)(buf + e * STR + p * 8);
    *(uint4*)(gout + (size_t)(e0 + e) * HID + p * 8) = v;
  }
}

// ---- prep1: unchanged (folds encoder+fuse, b67, W67; zeroes bnrep) ----
__global__ __launch_bounds__(128) void k_prep1(
    const float* __restrict__ emb, const float* __restrict__ conv_w,
    const float* __restrict__ conv_b, const float* __restrict__ fuse_w,
    const float* __restrict__ fuse_b,
    const float* __restrict__ fm_w1, const float* __restrict__ g2e_b2,
    const float* __restrict__ fm_b1, const float* __restrict__ w6,
    float* __restrict__ Mt, float* __restrict__ C0, float* __restrict__ Wnt,
    float* __restrict__ b67, float* __restrict__ W67, float* __restrict__ bnrep) {
  __shared__ float red[22][129];
  __shared__ float w7s[128];
  const int o = blockIdx.x;   // 0..127
  const int j = threadIdx.x;  // 0..127
  bnrep[o * 128 + j] = 0.f;
  float A[21];
  {
    float b0 = conv_b[j];
#pragma unroll
    for (int p = 0; p < 5; ++p) {
#pragma unroll
      for (int i = 0; i < 8; ++i) {
        float s = 0.f;
#pragma unroll
        for (int k = 0; k < 3; ++k) {
          int t = p + 1 - k;
          if (t >= 0 && t < 5) s += conv_w[(j * 8 + i) * 3 + k];
        }
        s *= 0.2f;
        if (i < 4) A[p * 4 + i] = s;
        else b0 += emb[p * 4 + (i - 4)] * s;
      }
    }
    A[20] = b0;
  }
  float w = fuse_w[o * 129 + j];
  float w7 = fm_w1[o * 128 + j];
  w7s[j] = w7;
#pragma unroll
  for (int qq = 0; qq < 21; ++qq) red[qq][j] = w * A[qq];
  red[21][j] = w7 * g2e_b2[j];
  __syncthreads();
  if (j < 22) {
    float s = 0.f;
    for (int t = 0; t < 128; ++t) s += red[j][t];
    if (j < 20)      Mt[j * 128 + o] = s;
    else if (j == 20) C0[o] = s + fuse_b[o];
    else              b67[o] = s + fm_b1[o];
  }
  if (j == 0) Wnt[o] = fuse_w[o * 129 + 128];
  float s = 0.f;
  for (int t = 0; t < 128; ++t) s += w7s[t] * w6[t * 128 + j];
  W67[o * 128 + j] = s;
}

// ---- prep2: blocks 0..39 pack 10 K=128 weight slices; blocks 40.. encode ----
struct PackArgs {
  const float* src[10];
  u16* dst[10];
  int stride[10];
  int koff[10];
};

__global__ __launch_bounds__(256) void k_prep2(
    PackArgs pa, const float* __restrict__ x, const float* __restrict__ node_type,
    const float* __restrict__ Mt, const float* __restrict__ C0,
    const float* __restrict__ Wnt, u16* __restrict__ h2) {
  if (blockIdx.x < 40) {  // ---- pack: matrix mi, K-chunk ks ----
    int mi = blockIdx.x >> 2, ks = blockIdx.x & 3;
    const float* W = pa.src[mi];
    u16* D = pa.dst[mi] + ks * 4096;
    const int stride = pa.stride[mi], koff = pa.koff[mi];
#pragma unroll
    for (int t = 0; t < 16; ++t) {
      int el = t * 256 + (int)threadIdx.x;
      int j = el & 7, ln = (el >> 3) & 63, ntile = el >> 9;
      int k = ks * 32 + ((ln >> 4) << 3) + j;   // 0..127 within slice
      int n = ntile * 16 + (ln & 15);
      D[el] = f2bf(W[n * stride + koff + k]);
    }
    return;
  }
  // ---- encode branch: 16 nodes per block ----
  __shared__ float xs[16][20], nts[16], mts[20 * 128];
  const int tid = threadIdx.x;
  const int n0 = ((int)blockIdx.x - 40) * 16;
  for (int i = tid; i < 320; i += 256) xs[i / 20][i % 20] = x[n0 * 20 + i];
  if (tid < 16) nts[tid] = node_type[n0 + tid];
  for (int i = tid; i < 2560; i += 256) mts[i] = Mt[i];
  __syncthreads();
  const int nl = tid >> 4;
  const int c0 = (tid & 15) * 8;
  float nt = nts[nl];
  union { u16 s[8]; uint4 u; } o;
#pragma unroll
  for (int i = 0; i < 8; ++i) {
    int ch = c0 + i;
    float acc = C0[ch] + Wnt[ch] * nt;
#pragma unroll
    for (int qq = 0; qq < 20; ++qq) acc += xs[nl][qq] * mts[qq * 128 + ch];
    o.s[i] = f2bf(acc);
  }
  *(uint4*)(h2 + (size_t)(n0 + nl) * HID + c0) = o.u;
}

// ---- dense node-GEMM pass: out = pW @ (rows staged in B0) ----
__device__ __forceinline__ void dense_pass(const u16* __restrict__ pW,
                                           u16* B0, u16* B1,
                                           u16* __restrict__ outT, int n0,
                                           int tid, int lane, int wave, int aoff) {
  f32x4 acc[4];
  zero_acc8(acc);
  wgemm8<4>(pW, [&](int ks, int mt) -> bf16x8 {
    return ld8(B0 + aoff + mt * 16 * STR + ks * 32);
  }, acc, lane, wave);
  __syncthreads();                  // prior flush's B1 reads complete
  epi_plain8(B1, acc, lane, wave);
  __syncthreads();
  flush_buf8(B1, outT, n0, tid);
}

// ---- k_pre: u = W1a@h2, v = W1b@h2, w = W3a@h2 (sequential rows, no gather) ----
__global__ __launch_bounds__(512, 4) void k_pre(
    const u16* __restrict__ h2, const u16* __restrict__ pW1a,
    const u16* __restrict__ pW1b, const u16* __restrict__ pW3a,
    u16* __restrict__ ut, u16* __restrict__ vt, u16* __restrict__ wt) {
  __shared__ __align__(16) u16 B0[64 * STR], B1[64 * STR];
  const int tid = threadIdx.x, lane = tid & 63, wave = tid >> 6;
  const int n0 = blockIdx.x * 64;
  const int aoff = (lane & 15) * STR + (lane >> 4) * 8;
#pragma unroll
  for (int it = 0; it < 2; ++it) {
    int cid = tid + it * 512, r = cid >> 4, p = cid & 15;
    int n = min(n0 + r, N_NODES - 1);
    uint4 v = *(const uint4*)(h2 + (size_t)n * HID + p * 8);
    *(uint4*)(B0 + r * STR + p * 8) = v;
  }
  __syncthreads();
  dense_pass(pW1a, B0, B1, ut, n0, tid, lane, wave, aoff);
  dense_pass(pW1b, B0, B1, vt, n0, tid, lane, wave, aoff);
  dense_pass(pW3a, B0, B1, wt, n0, tid, lane, wave, aoff);
}

// ---- k_pre2: za = W5a@h3, zb = W5b@h3 ----
__global__ __launch_bounds__(512, 4) void k_pre2(
    const u16* __restrict__ h3, const u16* __restrict__ pW5a,
    const u16* __restrict__ pW5b,
    u16* __restrict__ zat, u16* __restrict__ zbt) {
  __shared__ __align__(16) u16 B0[64 * STR], B1[64 * STR];
  const int tid = threadIdx.x, lane = tid & 63, wave = tid >> 6;
  const int n0 = blockIdx.x * 64;
  const int aoff = (lane & 15) * STR + (lane >> 4) * 8;
#pragma unroll
  for (int it = 0; it < 2; ++it) {
    int cid = tid + it * 512, r = cid >> 4, p = cid & 15;
    uint4 v = *(const uint4*)(h3 + (size_t)(n0 + r) * HID + p * 8);
    *(uint4*)(B0 + r * STR + p * 8) = v;
  }
  __syncthreads();
  dense_pass(pW5a, B0, B1, zat, n0, tid, lane, wave, aoff);
  dense_pass(pW5b, B0, B1, zbt, n0, tid, lane, wave, aoff);
}

// ---- gnn1: factored. H = relu(u[row]+v[col]+W1c*eattr+b1) via VALU;
// then GEMM2 (ea1), GEMM3b + w[row] add (H'), GEMM4 (h3). 12 ksteps vs 25. ----
__global__ __launch_bounds__(512, 4) void k_gnn1(
    const int* __restrict__ eidx, const float* __restrict__ eattr,
    const float* __restrict__ g1e_w1,
    const u16* __restrict__ ut, const u16* __restrict__ vt, const u16* __restrict__ wt,
    const u16* __restrict__ pW2, const u16* __restrict__ pW3b, const u16* __restrict__ pW4,
    const float* __restrict__ b1, const float* __restrict__ b2,
    const float* __restrict__ b3, const float* __restrict__ b4,
    u16* __restrict__ ea1, u16* __restrict__ h3) {
  __shared__ __align__(16) u16 B0[64 * STR], B1[64 * STR];
  const int tid = threadIdx.x, lane = tid & 63, wave = tid >> 6;
  const int e0 = blockIdx.x * 64;
  const int aoff = (lane & 15) * STR + (lane >> 4) * 8;
  const int* rowI = eidx;
  const int* colI = eidx + N_EDGES;

  // phase A: H directly from gathered u,v + eattr-term (no GEMM1 MFMA).
  {
    const int p = tid & 15, ch0 = p * 8;
    float4 wc0 = *(const float4*)(g1e_w1 + (ch0 + 0) * 260 + 256);
    float4 wc1 = *(const float4*)(g1e_w1 + (ch0 + 1) * 260 + 256);
    float4 wc2 = *(const float4*)(g1e_w1 + (ch0 + 2) * 260 + 256);
    float4 wc3 = *(const float4*)(g1e_w1 + (ch0 + 3) * 260 + 256);
    float4 wc4 = *(const float4*)(g1e_w1 + (ch0 + 4) * 260 + 256);
    float4 wc5 = *(const float4*)(g1e_w1 + (ch0 + 5) * 260 + 256);
    float4 wc6 = *(const float4*)(g1e_w1 + (ch0 + 6) * 260 + 256);
    float4 wc7 = *(const float4*)(g1e_w1 + (ch0 + 7) * 260 + 256);
    float4 bA = *(const float4*)(b1 + ch0);
    float4 bB = *(const float4*)(b1 + ch0 + 4);
    const float bb[8] = {bA.x, bA.y, bA.z, bA.w, bB.x, bB.y, bB.z, bB.w};
#pragma unroll
    for (int it = 0; it < 2; ++it) {
      int e = (tid >> 4) + it * 32;
      int row = rowI[e0 + e], col = colI[e0 + e];
      union { uint4 q; u16 s[8]; } U, V, O;
      U.q = *(const uint4*)(ut + (size_t)row * HID + ch0);
      V.q = *(const uint4*)(vt + (size_t)col * HID + ch0);
      float4 ea = *(const float4*)(eattr + (size_t)(e0 + e) * 4);
      const float4 wc[8] = {wc0, wc1, wc2, wc3, wc4, wc5, wc6, wc7};
#pragma unroll
      for (int i = 0; i < 8; ++i) {
        float c = ea.x * wc[i].x + ea.y * wc[i].y + ea.z * wc[i].z + ea.w * wc[i].w;
        float val = bf2f(U.s[i]) + bf2f(V.s[i]) + c + bb[i];
        O.s[i] = f2bf(fmaxf(val, 0.f));
      }
      *(uint4*)(B0 + e * STR + p * 8) = O.q;   // H -> B0
    }
  }
  __syncthreads();  // S1

  f32x4 acc[4];
  zero_acc8(acc);  // GEMM2: ea1 = W2 @ H
  wgemm8<4>(pW2, [&](int ks, int mt) -> bf16x8 {
    return ld8(B0 + aoff + mt * 16 * STR + ks * 32);
  }, acc, lane, wave);
  epi_store8<false>(B1, acc, b2, lane, wave);  // ea1 -> B1
  __syncthreads();  // S2
  flush_buf8(B1, ea1, e0, tid);

  if (e0 < N_NODES) {
    // stage w[row] -> B0 (B0's H fully consumed at S2)
#pragma unroll
    for (int it = 0; it < 2; ++it) {
      int cid = tid + it * 512, e = cid >> 4, p = cid & 15;
      int id = rowI[e0 + e];
      uint4 v = *(const uint4*)(wt + (size_t)id * HID + p * 8);
      *(uint4*)(B0 + e * STR + p * 8) = v;
    }
    __syncthreads();  // S3

    zero_acc8(acc);  // GEMM3b: W3b @ ea1 (A = B1)
    wgemm8<4>(pW3b, [&](int ks, int mt) -> bf16x8 {
      return ld8(B1 + aoff + mt * 16 * STR + ks * 32);
    }, acc, lane, wave);
    __syncthreads();  // S4 (all waves' B1 reads done)
    epi_add8<true>(B1, B0, acc, b3, lane, wave);  // H' = relu(acc + w + b3) -> B1
    __syncthreads();  // S5

    zero_acc8(acc);  // GEMM4: h3 = W4 @ H'
    wgemm8<4>(pW4, [&](int ks, int mt) -> bf16x8 {
      return ld8(B1 + aoff + mt * 16 * STR + ks * 32);
    }, acc, lane, wave);
    epi_store8<false>(B0, acc, b4, lane, wave);  // h3 -> B0
    __syncthreads();  // S6
    flush_buf8(B0, h3, e0, tid);
  }
}

// ---- gnn2: factored. H = relu(za[row]+zb[col] + W5c@ea1 + b5); z = W67@H. 8 ksteps. ----
__global__ __launch_bounds__(512, 4) void k_gnn2(
    const int* __restrict__ eidx,
    const u16* __restrict__ zat, const u16* __restrict__ zbt, u16* ea1z,
    const u16* __restrict__ pW5c, const u16* __restrict__ pW67,
    const float* __restrict__ b5, const float* __restrict__ b67,
    float* __restrict__ bnrep) {
  __shared__ __align__(16) u16 B0[64 * STR], B1[64 * STR];
  const int tid = threadIdx.x, lane = tid & 63, wave = tid >> 6;
  const int e0 = blockIdx.x * 64;
  const int m = lane & 15, q = lane >> 4;
  const int aoff = m * STR + q * 8;
  const int* rowI = eidx;
  const int* colI = eidx + N_EDGES;

  // stage: za[row]+zb[col] sum -> B1; ea1 tile -> B0
#pragma unroll
  for (int it = 0; it < 2; ++it) {
    int cid = tid + it * 512, e = cid >> 4, p = cid & 15;
    int row = rowI[e0 + e], col = colI[e0 + e];
    union { uint4 q; u16 s[8]; } A, B, O;
    A.q = *(const uint4*)(zat + (size_t)row * HID + p * 8);
    B.q = *(const uint4*)(zbt + (size_t)col * HID + p * 8);
#pragma unroll
    for (int i = 0; i < 8; ++i) O.s[i] = f2bf(bf2f(A.s[i]) + bf2f(B.s[i]));
    *(uint4*)(B1 + e * STR + p * 8) = O.q;
    uint4 z = *(const uint4*)(ea1z + (size_t)(e0 + e) * HID + p * 8);
    *(uint4*)(B0 + e * STR + p * 8) = z;
  }
  __syncthreads();  // S1

  f32x4 acc[4];
  zero_acc8(acc);  // GEMM1c: W5c @ ea1 (A = B0)
  wgemm8<4>(pW5c, [&](int ks, int mt) -> bf16x8 {
    return ld8(B0 + aoff + mt * 16 * STR + ks * 32);
  }, acc, lane, wave);
  __syncthreads();  // S2
  epi_add8<true>(B1, B1, acc, b5, lane, wave);  // H = relu(acc + (za+zb) + b5), in place
  __syncthreads();  // S3

  zero_acc8(acc);  // GEMM2': z = W67 @ H + b67
  wgemm8<4>(pW67, [&](int ks, int mt) -> bf16x8 {
    return ld8(B1 + aoff + mt * 16 * STR + ks * 32);
  }, acc, lane, wave);

  {
    const int c = lane & 15;
    const int col = wave * 16 + c;
    const float bb = b67[col];
    float s0 = 0.f, q0 = 0.f;
#pragma unroll
    for (int mt = 0; mt < 4; ++mt)
#pragma unroll
      for (int r = 0; r < 4; ++r) {
        float v0 = acc[mt][r] + bb;
        s0 += v0; q0 += v0 * v0;
        int row = mt * 16 + q * 4 + r;
        B0[row * STR + col] = f2bf(v0);
      }
    s0 += __shfl_xor(s0, 16); s0 += __shfl_xor(s0, 32);
    q0 += __shfl_xor(q0, 16); q0 += __shfl_xor(q0, 32);
    if (lane < 16) {
      float* slot = bnrep + ((int)blockIdx.x & (NREP - 1)) * 256;
      atomicAdd(&slot[wave * 16 + lane], s0);
      atomicAdd(&slot[128 + wave * 16 + lane], q0);
    }
  }
  __syncthreads();  // S4
  flush_buf8(B0, ea1z, e0, tid);
}

// ---- head: unchanged ----
__global__ __launch_bounds__(256) void k_head(const u16* __restrict__ z,
                                              const float* __restrict__ bnrep,
                                              const float* __restrict__ bn_g,
                                              const float* __restrict__ bn_b,
                                              const float* __restrict__ w2,
                                              const float* __restrict__ b2,
                                              float* __restrict__ out) {
  __shared__ float sh_s[128], sh_h[128], sh_w0[128], sh_w1[128], sh_w2[128];
  const int tid = threadIdx.x;
  {
    float s = 0.f;
    for (int r = 0; r < NREP; ++r) s += bnrep[r * 256 + tid];
    __shared__ float acc2[256];
    acc2[tid] = s;
    __syncthreads();
    if (tid < 128) {
      const float inv = 1.0f / (float)N_EDGES;
      float mu = acc2[tid] * inv;
      float var = acc2[128 + tid] * inv - mu * mu;
      float sc = bn_g[tid] * rsqrtf(var + 1e-5f);
      sh_s[tid] = sc;
      sh_h[tid] = bn_b[tid] - mu * sc;
      sh_w0[tid] = w2[tid];
      sh_w1[tid] = w2[128 + tid];
      sh_w2[tid] = w2[256 + tid];
    }
    __syncthreads();
  }
  const int lane = tid & 63, wave = tid >> 6;
  const int g = lane >> 4;
  const int p = lane & 15;
  const int c0 = p * 8;
  const float bb0 = b2[0], bb1 = b2[1], bb2 = b2[2];
#pragma unroll 4
  for (int it = 0; it < 16; ++it) {
    int e = (int)blockIdx.x * 256 + wave * 64 + it * 4 + g;
    if (e >= N_EDGES) break;
    uint4 v = *(const uint4*)(z + (size_t)e * HID + c0);
    unsigned wv[4] = {v.x, v.y, v.z, v.w};
    float a0 = 0.f, a1 = 0.f, a2 = 0.f;
#pragma unroll
    for (int k = 0; k < 4; ++k) {
      int ch = c0 + k * 2;
      float lo = bf2f(wv[k] & 0xffffu), hi = bf2f(wv[k] >> 16);
      float r0 = fmaxf(fmaf(lo, sh_s[ch], sh_h[ch]), 0.f);
      float r1 = fmaxf(fmaf(hi, sh_s[ch + 1], sh_h[ch + 1]), 0.f);
      a0 += r0 * sh_w0[ch] + r1 * sh_w0[ch + 1];
      a1 += r0 * sh_w1[ch] + r1 * sh_w1[ch + 1];
      a2 += r0 * sh_w2[ch] + r1 * sh_w2[ch + 1];
    }
#pragma unroll
    for (int off = 1; off < 16; off <<= 1) {
      a0 += __shfl_xor(a0, off);
      a1 += __shfl_xor(a1, off);
      a2 += __shfl_xor(a2, off);
    }
    if (p < 3) out[e * 3 + p] = (p == 0) ? a0 + bb0 : (p == 1) ? a1 + bb1 : a2 + bb2;
  }
}

extern "C" void kernel_launch(void* const* d_in, const int* in_sizes, int n_in,
                              void* d_out, int out_size, void* d_ws, size_t ws_size,
                              hipStream_t stream) {
  const float* x         = (const float*)d_in[0];
  const int* eidx        = (const int*)d_in[1];
  const float* eattr     = (const float*)d_in[2];
  const float* node_type = (const float*)d_in[4];
  const float* emb       = (const float*)d_in[5];
  const float* conv_w    = (const float*)d_in[6];
  const float* conv_b    = (const float*)d_in[7];
  const float* fuse_w    = (const float*)d_in[8];
  const float* fuse_b    = (const float*)d_in[9];
  const float* g1e_w1    = (const float*)d_in[10];
  const float* g1e_b1    = (const float*)d_in[11];
  const float* g1e_w2    = (const float*)d_in[12];
  const float* g1e_b2    = (const float*)d_in[13];
  const float* g1n_w1    = (const float*)d_in[14];
  const float* g1n_b1    = (const float*)d_in[15];
  const float* g1n_w2    = (const float*)d_in[16];
  const float* g1n_b2    = (const float*)d_in[17];
  const float* g2e_w1    = (const float*)d_in[18];
  const float* g2e_b1    = (const float*)d_in[19];
  const float* g2e_w2    = (const float*)d_in[20];
  const float* g2e_b2    = (const float*)d_in[21];
  // d_in[22..25] = g2n_* : dead code in the reference (output unused)
  const float* fm_w1     = (const float*)d_in[26];
  const float* fm_b1     = (const float*)d_in[27];
  const float* bn_g      = (const float*)d_in[28];
  const float* bn_b      = (const float*)d_in[29];
  const float* fm_w2     = (const float*)d_in[30];
  const float* fm_b2     = (const float*)d_in[31];
  float* out = (float*)d_out;

  char* ws = (char*)d_ws;
  size_t off = 0;
  auto take = [&](size_t bytes) {
    void* p = ws + off;
    off = (off + bytes + 255) & ~(size_t)255;
    return p;
  };
  u16* h2   = (u16*)take((size_t)N_NODES * HID * 2);
  u16* h3   = (u16*)take((size_t)20032 * HID * 2);
  u16* ea1z = (u16*)take((size_t)N_EDGES * HID * 2);
  u16* ut   = (u16*)take((size_t)20032 * HID * 2);
  u16* vt   = (u16*)take((size_t)20032 * HID * 2);
  u16* wt   = (u16*)take((size_t)20032 * HID * 2);
  u16* zat  = (u16*)take((size_t)20032 * HID * 2);
  u16* zbt  = (u16*)take((size_t)20032 * HID * 2);
  float* Mt    = (float*)take(20 * 128 * 4);
  float* C0    = (float*)take(128 * 4);
  float* Wnt   = (float*)take(128 * 4);
  float* b67   = (float*)take(128 * 4);
  float* W67f  = (float*)take(128 * 128 * 4);
  float* bnrep = (float*)take((size_t)NREP * 256 * 4);
  u16* pW1a = (u16*)take(4 * 4096 * 2);
  u16* pW1b = (u16*)take(4 * 4096 * 2);
  u16* pW3a = (u16*)take(4 * 4096 * 2);
  u16* pW3b = (u16*)take(4 * 4096 * 2);
  u16* pW2  = (u16*)take(4 * 4096 * 2);
  u16* pW4  = (u16*)take(4 * 4096 * 2);
  u16* pW5a = (u16*)take(4 * 4096 * 2);
  u16* pW5b = (u16*)take(4 * 4096 * 2);
  u16* pW5c = (u16*)take(4 * 4096 * 2);
  u16* pW67 = (u16*)take(4 * 4096 * 2);

  k_prep1<<<128, 128, 0, stream>>>(emb, conv_w, conv_b, fuse_w, fuse_b,
                                   fm_w1, g2e_b2, fm_b1, g2e_w2,
                                   Mt, C0, Wnt, b67, W67f, bnrep);

  PackArgs pa;
  const float* srcs[10] = {g1e_w1, g1e_w1, g1n_w1, g1n_w1, g1e_w2,
                           g1n_w2, g2e_w1, g2e_w1, g2e_w1, W67f};
  u16* dsts[10] = {pW1a, pW1b, pW3a, pW3b, pW2, pW4, pW5a, pW5b, pW5c, pW67};
  int strd[10] = {260, 260, 256, 256, 128, 128, 384, 384, 384, 128};
  int kofs[10] = {0, 128, 0, 128, 0, 0, 0, 128, 256, 0};
  for (int i = 0; i < 10; ++i) {
    pa.src[i] = srcs[i]; pa.dst[i] = dsts[i];
    pa.stride[i] = strd[i]; pa.koff[i] = kofs[i];
  }

  k_prep2<<<40 + N_NODES / 16, 256, 0, stream>>>(pa, x, node_type, Mt, C0, Wnt, h2);
  k_pre<<<NPRE, 512, 0, stream>>>(h2, pW1a, pW1b, pW3a, ut, vt, wt);
  k_gnn1<<<NBLK, 512, 0, stream>>>(eidx, eattr, g1e_w1, ut, vt, wt,
                                   pW2, pW3b, pW4,
                                   g1e_b1, g1e_b2, g1n_b1, g1n_b2, ea1z, h3);
  k_pre2<<<NPRE, 512, 0, stream>>>(h3, pW5a, pW5b, zat, zbt);
  k_gnn2<<<NBLK, 512, 0, stream>>>(eidx, zat, zbt, ea1z, pW5c, pW67,
                                   g2e_b1, b67, bnrep);
  k_head<<<(N_EDGES + 255) / 256, 256, 0, stream>>>(ea1z, bnrep, bn_g, bn_b,
                                                    fm_w2, fm_b2, out);
}

// Round 11
// 251.403 us; speedup vs baseline: 1.0169x; 1.0169x over previous
//
#include <hip/hip_runtime.h>

#define N_NODES 20000
#define N_EDGES 200000
#define HID 128
#define STR 136    // LDS row stride in u16: 272B rows -> every b128 access 16B-aligned
#define NBLKG 1563 // 2-tile gnn blocks: ceil(3125/2)
#define NREP 64    // BN accumulator replicas

typedef unsigned short u16;
using bf16x8 = __attribute__((ext_vector_type(8))) __bf16;
using f32x4  = __attribute__((ext_vector_type(4))) float;

__device__ __forceinline__ u16 f2bf(float f) {
  union { float f; unsigned u; } v; v.f = f;
  unsigned u = v.u;
  return (u16)((u + 0x7FFFu + ((u >> 16) & 1u)) >> 16);
}
__device__ __forceinline__ float bf2f(unsigned s) {
  union { unsigned u; float f; } v; v.u = s << 16;
  return v.f;
}
__device__ __forceinline__ bf16x8 ld8(const u16* p) { return *(const bf16x8*)p; }

// LDS-only barrier: does NOT drain vmcnt (T4). Memory-clobber asm on both
// sides blocks compiler reordering of LDS/global ops across it (m152 safety);
// in-flight global loads/stores (prefetch, flushes) ride through.
__device__ __forceinline__ void bar_lds() {
  asm volatile("s_waitcnt lgkmcnt(0)" ::: "memory");
  __builtin_amdgcn_s_barrier();
  asm volatile("" ::: "memory");
}

__device__ __forceinline__ void zero_acc8(f32x4 acc[4]) {
#pragma unroll
  for (int i = 0; i < 4; ++i) acc[i] = (f32x4){0.f, 0.f, 0.f, 0.f};
}

// r4-proven: depth-1 B prefetch, 8-wave, wave w owns cols w*16..w*16+15.
template <int KSTEPS, typename AF>
__device__ __forceinline__ void wgemm8(const u16* __restrict__ PW, AF afrag,
                                       f32x4 acc[4], int lane, int wave) {
  const u16* pb = PW + (wave * 64 + lane) * 8;
  bf16x8 b[2];
  b[0] = ld8(pb);
#pragma unroll
  for (int ks = 0; ks < KSTEPS; ++ks) {
    const int cur = ks & 1;
    if (ks + 1 < KSTEPS) b[cur ^ 1] = ld8(pb + (ks + 1) * 4096);
#pragma unroll
    for (int mt = 0; mt < 4; ++mt) {
      bf16x8 a = afrag(ks, mt);
      acc[mt] = __builtin_amdgcn_mfma_f32_16x16x32_bf16(a, b[cur], acc[mt], 0, 0, 0);
    }
  }
}

// C/D: row(edge) = mt*16 + (lane>>4)*4 + r, col(ch) = wave*16 + (lane&15).
template <bool RELU>
__device__ __forceinline__ void epi_store8(u16* buf, const f32x4 acc[4],
                                           const float* __restrict__ bias,
                                           int lane, int wave) {
  const int c = lane & 15, q = lane >> 4;
  const float bb = bias[wave * 16 + c];
  const int col = wave * 16 + c;
#pragma unroll
  for (int mt = 0; mt < 4; ++mt)
#pragma unroll
    for (int r = 0; r < 4; ++r) {
      float v = acc[mt][r] + bb;
      if (RELU) v = fmaxf(v, 0.f);
      buf[(mt * 16 + q * 4 + r) * STR + col] = f2bf(v);
    }
}

__device__ __forceinline__ void flush_buf8(const u16* buf, u16* __restrict__ gout,
                                           int e0, int tid) {
#pragma unroll
  for (int it = 0; it < 2; ++it) {
    int cid = tid + it * 512, e = cid >> 4, p = cid & 15;
    uint4 v = *(const uint4*)(buf + e * STR + p * 8);
    *(uint4*)(gout + (size_t)(e0 + e) * HID + p * 8) = v;
  }
}

// 8-wave gather: 128 rows (64 B0 + 64 B1), 16 rows per wave, 16 lanes/row.
__device__ __forceinline__ void stage_gather8(const int* __restrict__ rowI,
                                              const int* __restrict__ colI,
                                              const u16* __restrict__ htab,
                                              u16* B0, u16* B1,
                                              int e0, int lane, int wave) {
  const int r = lane >> 4, p = lane & 15;
#pragma unroll
  for (int it = 0; it < 4; ++it) {
    int j = wave * 16 + it * 4 + r;  // 0..127
    int e = j & 63;
    int id = (j < 64) ? rowI[e0 + e] : colI[e0 + e];
    uint4 v = *(const uint4*)(htab + (size_t)id * HID + p * 8);
    *(uint4*)(((j < 64) ? B0 : B1) + e * STR + p * 8) = v;
  }
}

__device__ __forceinline__ void make_ef(bf16x8 ef[4], const float* __restrict__ eattr,
                                        int e0, int m, int q) {
#pragma unroll
  for (int mt = 0; mt < 4; ++mt) {
    union { u16 s[8]; uint4 u; bf16x8 v; } t;
    t.u = make_uint4(0u, 0u, 0u, 0u);
    if (q == 0) {
      float4 a = *(const float4*)(eattr + (size_t)(e0 + mt * 16 + m) * 4);
      t.s[0] = f2bf(a.x); t.s[1] = f2bf(a.y); t.s[2] = f2bf(a.z); t.s[3] = f2bf(a.w);
    }
    ef[mt] = t.v;
  }
}

// ---- prep1: one block per output channel o (folds encoder+fuse, b67, W67;
// zeroes bnrep) ----
__global__ __launch_bounds__(128) void k_prep1(
    const float* __restrict__ emb, const float* __restrict__ conv_w,
    const float* __restrict__ conv_b, const float* __restrict__ fuse_w,
    const float* __restrict__ fuse_b,
    const float* __restrict__ fm_w1, const float* __restrict__ g2e_b2,
    const float* __restrict__ fm_b1, const float* __restrict__ w6,
    float* __restrict__ Mt, float* __restrict__ C0, float* __restrict__ Wnt,
    float* __restrict__ b67, float* __restrict__ W67, float* __restrict__ bnrep) {
  __shared__ float red[22][129];
  __shared__ float w7s[128];
  const int o = blockIdx.x;   // 0..127
  const int j = threadIdx.x;  // 0..127
  bnrep[o * 128 + j] = 0.f;
  float A[21];
  {
    float b0 = conv_b[j];
#pragma unroll
    for (int p = 0; p < 5; ++p) {
#pragma unroll
      for (int i = 0; i < 8; ++i) {
        float s = 0.f;
#pragma unroll
        for (int k = 0; k < 3; ++k) {
          int t = p + 1 - k;
          if (t >= 0 && t < 5) s += conv_w[(j * 8 + i) * 3 + k];
        }
        s *= 0.2f;
        if (i < 4) A[p * 4 + i] = s;
        else b0 += emb[p * 4 + (i - 4)] * s;
      }
    }
    A[20] = b0;
  }
  float w = fuse_w[o * 129 + j];
  float w7 = fm_w1[o * 128 + j];
  w7s[j] = w7;
#pragma unroll
  for (int qq = 0; qq < 21; ++qq) red[qq][j] = w * A[qq];
  red[21][j] = w7 * g2e_b2[j];
  __syncthreads();
  if (j < 22) {
    float s = 0.f;
    for (int t = 0; t < 128; ++t) s += red[j][t];
    if (j < 20)      Mt[j * 128 + o] = s;
    else if (j == 20) C0[o] = s + fuse_b[o];
    else              b67[o] = s + fm_b1[o];
  }
  if (j == 0) Wnt[o] = fuse_w[o * 129 + 128];
  float s = 0.f;
  for (int t = 0; t < 128; ++t) s += w7s[t] * w6[t * 128 + j];
  W67[o * 128 + j] = s;
}

// ---- prep2: blocks 0..40 pack weights; blocks 41.. encode nodes ----
struct PackArgs {
  const float* src[6];
  u16* dst[6];
  int Kin[6];
  int ksCum[7];
};

__global__ __launch_bounds__(256) void k_prep2(
    PackArgs pa, const float* __restrict__ x, const float* __restrict__ node_type,
    const float* __restrict__ Mt, const float* __restrict__ C0,
    const float* __restrict__ Wnt, u16* __restrict__ h2) {
  if (blockIdx.x < 41) {
    int bk = blockIdx.x;
    int mi = 0;
    while (bk >= pa.ksCum[mi + 1]) ++mi;
    int ks = bk - pa.ksCum[mi];
    const float* W = pa.src[mi];
    u16* D = pa.dst[mi] + ks * 4096;
    int Kin = pa.Kin[mi];
#pragma unroll
    for (int t = 0; t < 16; ++t) {
      int el = t * 256 + (int)threadIdx.x;
      int j = el & 7, ln = (el >> 3) & 63, ntile = el >> 9;
      int k = ks * 32 + ((ln >> 4) << 3) + j;
      int n = ntile * 16 + (ln & 15);
      float v = (k < Kin) ? W[n * Kin + k] : 0.0f;
      D[el] = f2bf(v);
    }
    return;
  }
  __shared__ float xs[16][20], nts[16], mts[20 * 128];
  const int tid = threadIdx.x;
  const int n0 = ((int)blockIdx.x - 41) * 16;
  for (int i = tid; i < 320; i += 256) xs[i / 20][i % 20] = x[n0 * 20 + i];
  if (tid < 16) nts[tid] = node_type[n0 + tid];
  for (int i = tid; i < 2560; i += 256) mts[i] = Mt[i];
  __syncthreads();
  const int nl = tid >> 4;
  const int c0 = (tid & 15) * 8;
  float nt = nts[nl];
  union { u16 s[8]; uint4 u; } o;
#pragma unroll
  for (int i = 0; i < 8; ++i) {
    int ch = c0 + i;
    float acc = C0[ch] + Wnt[ch] * nt;
#pragma unroll
    for (int qq = 0; qq < 20; ++qq) acc += xs[nl][qq] * mts[qq * 128 + ch];
    o.s[i] = f2bf(acc);
  }
  *(uint4*)(h2 + (size_t)(n0 + nl) * HID + c0) = o.u;
}

// ---- gnn1 chain (r4 logic + B1-cycling: h2[row] stays in B0 through GEMM3;
// the old S5 re-gather is deleted). All barriers LDS-only. ----
template <typename H1>
__device__ __forceinline__ void gnn1_chain(
    u16* B0, u16* B1, const bf16x8 ef[4],
    const u16* __restrict__ pW1, const u16* __restrict__ pW2,
    const u16* __restrict__ pW3, const u16* __restrict__ pW4,
    const float* __restrict__ b1, const float* __restrict__ b2,
    const float* __restrict__ b3, const float* __restrict__ b4,
    u16* __restrict__ ea1, u16* __restrict__ h3,
    int e0, int tid, int lane, int wave, int aoff, H1 issue) {
  f32x4 acc[4];
  zero_acc8(acc);
  issue();   // tile A: launch tile-B gather prefetch (rides across bar_lds)
  wgemm8<9>(pW1, [&](int ks, int mt) -> bf16x8 {
    if (ks < 4) return ld8(B0 + aoff + mt * 16 * STR + ks * 32);
    if (ks < 8) return ld8(B1 + aoff + mt * 16 * STR + (ks - 4) * 32);
    return ef[mt];
  }, acc, lane, wave);
  bar_lds();                                   // S2
  epi_store8<true>(B1, acc, b1, lane, wave);   // H -> B1
  bar_lds();                                   // S3
  zero_acc8(acc);
  wgemm8<4>(pW2, [&](int ks, int mt) -> bf16x8 {
    return ld8(B1 + aoff + mt * 16 * STR + ks * 32);
  }, acc, lane, wave);
  bar_lds();                                   // S4 (H reads done)
  epi_store8<false>(B1, acc, b2, lane, wave);  // ea1 -> B1 (in place)
  bar_lds();                                   // S5
  flush_buf8(B1, ea1, e0, tid);
  if (e0 < N_NODES) {
    zero_acc8(acc);
    wgemm8<8>(pW3, [&](int ks, int mt) -> bf16x8 {
      if (ks < 4) return ld8(B0 + aoff + mt * 16 * STR + ks * 32);  // h2[row] retained
      return ld8(B1 + aoff + mt * 16 * STR + (ks - 4) * 32);        // ea1
    }, acc, lane, wave);
    bar_lds();                                 // S6
    epi_store8<true>(B1, acc, b3, lane, wave); // H' -> B1
    bar_lds();                                 // S7
    zero_acc8(acc);
    wgemm8<4>(pW4, [&](int ks, int mt) -> bf16x8 {
      return ld8(B1 + aoff + mt * 16 * STR + ks * 32);
    }, acc, lane, wave);
    epi_store8<false>(B0, acc, b4, lane, wave); // h3 -> B0 (h2row dead)
    bar_lds();                                 // S8
    flush_buf8(B0, h3, e0, tid);
  }
}

__global__ __launch_bounds__(512, 4) void k_gnn1(
    const int* __restrict__ eidx, const float* __restrict__ eattr,
    const u16* __restrict__ h2, const u16* __restrict__ pW1, const u16* __restrict__ pW2,
    const u16* __restrict__ pW3, const u16* __restrict__ pW4, const float* __restrict__ b1,
    const float* __restrict__ b2, const float* __restrict__ b3, const float* __restrict__ b4,
    u16* __restrict__ ea1, u16* __restrict__ h3) {
  __shared__ __align__(16) u16 B0[64 * STR], B1[64 * STR];
  const int tid = threadIdx.x, lane = tid & 63, wave = tid >> 6;
  const int e0 = (int)blockIdx.x * 128;
  const int e1 = e0 + 64;
  const bool hasB = (e1 < N_EDGES);
  const int m = lane & 15, q = lane >> 4;
  const int aoff = m * STR + q * 8;
  const int* rowI = eidx;
  const int* colI = eidx + N_EDGES;
  const int jr = lane >> 4, jp = lane & 15;
  const int j0 = wave * 16 + jr, j1 = j0 + 4, j2 = j0 + 8, j3 = j0 + 12;

  stage_gather8(rowI, colI, h2, B0, B1, e0, lane, wave);
  bf16x8 ef[4];
  make_ef(ef, eattr, e0, m, q);
  // tile-B index prefetch (pre-S1: bar_lds does not drain these)
  int i0 = 0, i1 = 0, i2 = 0, i3 = 0;
  if (hasB) {
    i0 = ((j0 < 64) ? rowI : colI)[e1 + (j0 & 63)];
    i1 = ((j1 < 64) ? rowI : colI)[e1 + (j1 & 63)];
    i2 = ((j2 < 64) ? rowI : colI)[e1 + (j2 & 63)];
    i3 = ((j3 < 64) ? rowI : colI)[e1 + (j3 & 63)];
  }
  bar_lds();  // S1

  uint4 g0, g1, g2, g3;
  gnn1_chain(B0, B1, ef, pW1, pW2, pW3, pW4, b1, b2, b3, b4,
             ea1, h3, e0, tid, lane, wave, aoff, [&]() {
    if (hasB) {
      g0 = *(const uint4*)(h2 + (size_t)i0 * HID + jp * 8);
      g1 = *(const uint4*)(h2 + (size_t)i1 * HID + jp * 8);
      g2 = *(const uint4*)(h2 + (size_t)i2 * HID + jp * 8);
      g3 = *(const uint4*)(h2 + (size_t)i3 * HID + jp * 8);
    }
  });

  if (hasB) {
    bar_lds();  // S9: tile-A LDS reads complete
    *(uint4*)(((j0 < 64) ? B0 : B1) + (j0 & 63) * STR + jp * 8) = g0;
    *(uint4*)(((j1 < 64) ? B0 : B1) + (j1 & 63) * STR + jp * 8) = g1;
    *(uint4*)(((j2 < 64) ? B0 : B1) + (j2 & 63) * STR + jp * 8) = g2;
    *(uint4*)(((j3 < 64) ? B0 : B1) + (j3 & 63) * STR + jp * 8) = g3;
    bf16x8 efB[4];
    make_ef(efB, eattr, e1, m, q);
    bar_lds();  // S1'
    gnn1_chain(B0, B1, efB, pW1, pW2, pW3, pW4, b1, b2, b3, b4,
               ea1, h3, e1, tid, lane, wave, aoff, []() {});
  }
}

// ---- gnn2 chain ----
template <typename H1, typename SZ>
__device__ __forceinline__ void gnn2_chain(
    u16* B0, u16* B1,
    const u16* __restrict__ pW5, const u16* __restrict__ pW67,
    const float* __restrict__ b5, const float* __restrict__ b67,
    float* __restrict__ bnrep, u16* __restrict__ ea1z, int e0, int slot,
    int tid, int lane, int wave, int aoff, H1 issue, SZ stageZ) {
  const int q = lane >> 4;
  f32x4 acc[4];
  zero_acc8(acc);
  issue();
  wgemm8<8>(pW5, [&](int ks, int mt) -> bf16x8 {
    if (ks < 4) return ld8(B0 + aoff + mt * 16 * STR + ks * 32);
    return ld8(B1 + aoff + mt * 16 * STR + (ks - 4) * 32);
  }, acc, lane, wave);
  bar_lds();            // S2
  stageZ();             // ea1 tile -> B0 (global loads for tile A; regs for tile B)
  bar_lds();            // S3
  wgemm8<4>(pW5 + 8 * 4096, [&](int ks, int mt) -> bf16x8 {
    return ld8(B0 + aoff + mt * 16 * STR + ks * 32);
  }, acc, lane, wave);
  epi_store8<true>(B1, acc, b5, lane, wave);  // H -> B1
  bar_lds();            // S4
  zero_acc8(acc);
  wgemm8<4>(pW67, [&](int ks, int mt) -> bf16x8 {
    return ld8(B1 + aoff + mt * 16 * STR + ks * 32);
  }, acc, lane, wave);
  {
    const int c = lane & 15;
    const int col = wave * 16 + c;
    const float bb = b67[col];
    float s0 = 0.f, q0 = 0.f;
#pragma unroll
    for (int mt = 0; mt < 4; ++mt)
#pragma unroll
      for (int r = 0; r < 4; ++r) {
        float v0 = acc[mt][r] + bb;
        s0 += v0; q0 += v0 * v0;
        int row = mt * 16 + q * 4 + r;
        B0[row * STR + col] = f2bf(v0);
      }
    s0 += __shfl_xor(s0, 16); s0 += __shfl_xor(s0, 32);
    q0 += __shfl_xor(q0, 16); q0 += __shfl_xor(q0, 32);
    if (lane < 16) {
      float* sl = bnrep + slot * 256;
      atomicAdd(&sl[wave * 16 + lane], s0);
      atomicAdd(&sl[128 + wave * 16 + lane], q0);
    }
  }
  bar_lds();            // S5
  flush_buf8(B0, ea1z, e0, tid);
}

__global__ __launch_bounds__(512, 4) void k_gnn2(
    const int* __restrict__ eidx, const u16* __restrict__ h3, u16* ea1z,
    const u16* __restrict__ pW5, const u16* __restrict__ pW67,
    const float* __restrict__ b5, const float* __restrict__ b67,
    float* __restrict__ bnrep) {
  __shared__ __align__(16) u16 B0[64 * STR], B1[64 * STR];
  const int tid = threadIdx.x, lane = tid & 63, wave = tid >> 6;
  const int e0 = (int)blockIdx.x * 128;
  const int e1 = e0 + 64;
  const bool hasB = (e1 < N_EDGES);
  const int m = lane & 15, q = lane >> 4;
  const int aoff = m * STR + q * 8;
  const int* rowI = eidx;
  const int* colI = eidx + N_EDGES;
  const int jr = lane >> 4, jp = lane & 15;
  const int j0 = wave * 16 + jr, j1 = j0 + 4, j2 = j0 + 8, j3 = j0 + 12;
  const int ez = tid >> 4, pz = tid & 15;

  stage_gather8(rowI, colI, h3, B0, B1, e0, lane, wave);
  int i0 = 0, i1 = 0, i2 = 0, i3 = 0;
  if (hasB) {
    i0 = ((j0 < 64) ? rowI : colI)[e1 + (j0 & 63)];
    i1 = ((j1 < 64) ? rowI : colI)[e1 + (j1 & 63)];
    i2 = ((j2 < 64) ? rowI : colI)[e1 + (j2 & 63)];
    i3 = ((j3 < 64) ? rowI : colI)[e1 + (j3 & 63)];
  }
  bar_lds();  // S1

  uint4 g0, g1, g2, g3, za, zb;
  gnn2_chain(B0, B1, pW5, pW67, b5, b67, bnrep, ea1z, e0,
             (2 * (int)blockIdx.x) & (NREP - 1), tid, lane, wave, aoff,
    [&]() {   // issue: tile-B gather + ea1 prefetch
      if (hasB) {
        g0 = *(const uint4*)(h3 + (size_t)i0 * HID + jp * 8);
        g1 = *(const uint4*)(h3 + (size_t)i1 * HID + jp * 8);
        g2 = *(const uint4*)(h3 + (size_t)i2 * HID + jp * 8);
        g3 = *(const uint4*)(h3 + (size_t)i3 * HID + jp * 8);
        za = *(const uint4*)(ea1z + (size_t)(e1 + ez) * HID + pz * 8);
        zb = *(const uint4*)(ea1z + (size_t)(e1 + 32 + ez) * HID + pz * 8);
      }
    },
    [&]() {   // stageZ (tile A): global ea1 -> B0
#pragma unroll
      for (int it = 0; it < 2; ++it) {
        int cid = tid + it * 512, e = cid >> 4, p = cid & 15;
        uint4 v = *(const uint4*)(ea1z + (size_t)(e0 + e) * HID + p * 8);
        *(uint4*)(B0 + e * STR + p * 8) = v;
      }
    });

  if (hasB) {
    bar_lds();  // S6
    *(uint4*)(((j0 < 64) ? B0 : B1) + (j0 & 63) * STR + jp * 8) = g0;
    *(uint4*)(((j1 < 64) ? B0 : B1) + (j1 & 63) * STR + jp * 8) = g1;
    *(uint4*)(((j2 < 64) ? B0 : B1) + (j2 & 63) * STR + jp * 8) = g2;
    *(uint4*)(((j3 < 64) ? B0 : B1) + (j3 & 63) * STR + jp * 8) = g3;
    bar_lds();  // S1'
    gnn2_chain(B0, B1, pW5, pW67, b5, b67, bnrep, ea1z, e1,
               (2 * (int)blockIdx.x + 1) & (NREP - 1), tid, lane, wave, aoff,
      []() {},
      [&]() {   // stageZ (tile B): held regs -> B0
        *(uint4*)(B0 + ez * STR + pz * 8) = za;
        *(uint4*)(B0 + (32 + ez) * STR + pz * 8) = zb;
      });
  }
}

// ---- head: unchanged ----
__global__ __launch_bounds__(256) void k_head(const u16* __restrict__ z,
                                              const float* __restrict__ bnrep,
                                              const float* __restrict__ bn_g,
                                              const float* __restrict__ bn_b,
                                              const float* __restrict__ w2,
                                              const float* __restrict__ b2,
                                              float* __restrict__ out) {
  __shared__ float sh_s[128], sh_h[128], sh_w0[128], sh_w1[128], sh_w2[128];
  const int tid = threadIdx.x;
  {
    float s = 0.f;
    for (int r = 0; r < NREP; ++r) s += bnrep[r * 256 + tid];
    __shared__ float acc2[256];
    acc2[tid] = s;
    __syncthreads();
    if (tid < 128) {
      const float inv = 1.0f / (float)N_EDGES;
      float mu = acc2[tid] * inv;
      float var = acc2[128 + tid] * inv - mu * mu;
      float sc = bn_g[tid] * rsqrtf(var + 1e-5f);
      sh_s[tid] = sc;
      sh_h[tid] = bn_b[tid] - mu * sc;
      sh_w0[tid] = w2[tid];
      sh_w1[tid] = w2[128 + tid];
      sh_w2[tid] = w2[256 + tid];
    }
    __syncthreads();
  }
  const int lane = tid & 63, wave = tid >> 6;
  const int g = lane >> 4;
  const int p = lane & 15;
  const int c0 = p * 8;
  const float bb0 = b2[0], bb1 = b2[1], bb2 = b2[2];
#pragma unroll 4
  for (int it = 0; it < 16; ++it) {
    int e = (int)blockIdx.x * 256 + wave * 64 + it * 4 + g;
    if (e >= N_EDGES) break;
    uint4 v = *(const uint4*)(z + (size_t)e * HID + c0);
    unsigned wv[4] = {v.x, v.y, v.z, v.w};
    float a0 = 0.f, a1 = 0.f, a2 = 0.f;
#pragma unroll
    for (int k = 0; k < 4; ++k) {
      int ch = c0 + k * 2;
      float lo = bf2f(wv[k] & 0xffffu), hi = bf2f(wv[k] >> 16);
      float r0 = fmaxf(fmaf(lo, sh_s[ch], sh_h[ch]), 0.f);
      float r1 = fmaxf(fmaf(hi, sh_s[ch + 1], sh_h[ch + 1]), 0.f);
      a0 += r0 * sh_w0[ch] + r1 * sh_w0[ch + 1];
      a1 += r0 * sh_w1[ch] + r1 * sh_w1[ch + 1];
      a2 += r0 * sh_w2[ch] + r1 * sh_w2[ch + 1];
    }
#pragma unroll
    for (int off = 1; off < 16; off <<= 1) {
      a0 += __shfl_xor(a0, off);
      a1 += __shfl_xor(a1, off);
      a2 += __shfl_xor(a2, off);
    }
    if (p < 3) out[e * 3 + p] = (p == 0) ? a0 + bb0 : (p == 1) ? a1 + bb1 : a2 + bb2;
  }
}

extern "C" void kernel_launch(void* const* d_in, const int* in_sizes, int n_in,
                              void* d_out, int out_size, void* d_ws, size_t ws_size,
                              hipStream_t stream) {
  const float* x         = (const float*)d_in[0];
  const int* eidx        = (const int*)d_in[1];
  const float* eattr     = (const float*)d_in[2];
  const float* node_type = (const float*)d_in[4];
  const float* emb       = (const float*)d_in[5];
  const float* conv_w    = (const float*)d_in[6];
  const float* conv_b    = (const float*)d_in[7];
  const float* fuse_w    = (const float*)d_in[8];
  const float* fuse_b    = (const float*)d_in[9];
  const float* g1e_w1    = (const float*)d_in[10];
  const float* g1e_b1    = (const float*)d_in[11];
  const float* g1e_w2    = (const float*)d_in[12];
  const float* g1e_b2    = (const float*)d_in[13];
  const float* g1n_w1    = (const float*)d_in[14];
  const float* g1n_b1    = (const float*)d_in[15];
  const float* g1n_w2    = (const float*)d_in[16];
  const float* g1n_b2    = (const float*)d_in[17];
  const float* g2e_w1    = (const float*)d_in[18];
  const float* g2e_b1    = (const float*)d_in[19];
  const float* g2e_w2    = (const float*)d_in[20];
  const float* g2e_b2    = (const float*)d_in[21];
  // d_in[22..25] = g2n_* : dead code in the reference (output unused)
  const float* fm_w1     = (const float*)d_in[26];
  const float* fm_b1     = (const float*)d_in[27];
  const float* bn_g      = (const float*)d_in[28];
  const float* bn_b      = (const float*)d_in[29];
  const float* fm_w2     = (const float*)d_in[30];
  const float* fm_b2     = (const float*)d_in[31];
  float* out = (float*)d_out;

  char* ws = (char*)d_ws;
  size_t off = 0;
  auto take = [&](size_t bytes) {
    void* p = ws + off;
    off = (off + bytes + 255) & ~(size_t)255;
    return p;
  };
  u16* h2   = (u16*)take((size_t)N_NODES * HID * 2);
  u16* h3   = (u16*)take((size_t)20032 * HID * 2);
  u16* ea1z = (u16*)take((size_t)N_EDGES * HID * 2);
  float* Mt    = (float*)take(20 * 128 * 4);
  float* C0    = (float*)take(128 * 4);
  float* Wnt   = (float*)take(128 * 4);
  float* b67   = (float*)take(128 * 4);
  float* W67f  = (float*)take(128 * 128 * 4);
  float* bnrep = (float*)take((size_t)NREP * 256 * 4);
  u16* pW1  = (u16*)take(9 * 4096 * 2);
  u16* pW2  = (u16*)take(4 * 4096 * 2);
  u16* pW3  = (u16*)take(8 * 4096 * 2);
  u16* pW4  = (u16*)take(4 * 4096 * 2);
  u16* pW5  = (u16*)take(12 * 4096 * 2);
  u16* pW67 = (u16*)take(4 * 4096 * 2);

  k_prep1<<<128, 128, 0, stream>>>(emb, conv_w, conv_b, fuse_w, fuse_b,
                                   fm_w1, g2e_b2, fm_b1, g2e_w2,
                                   Mt, C0, Wnt, b67, W67f, bnrep);

  PackArgs pa;
  const float* srcs[6] = {g1e_w1, g1e_w2, g1n_w1, g1n_w2, g2e_w1, W67f};
  u16* dsts[6] = {pW1, pW2, pW3, pW4, pW5, pW67};
  int kins[6] = {260, 128, 256, 128, 384, 128};
  int kst[6] = {9, 4, 8, 4, 12, 4};
  int cum = 0;
  for (int i = 0; i < 6; ++i) {
    pa.src[i] = srcs[i]; pa.dst[i] = dsts[i]; pa.Kin[i] = kins[i];
    pa.ksCum[i] = cum; cum += kst[i];
  }
  pa.ksCum[6] = cum;  // 41

  k_prep2<<<41 + N_NODES / 16, 256, 0, stream>>>(pa, x, node_type, Mt, C0, Wnt, h2);
  k_gnn1<<<NBLKG, 512, 0, stream>>>(eidx, eattr, h2, pW1, pW2, pW3, pW4,
                                    g1e_b1, g1e_b2, g1n_b1, g1n_b2, ea1z, h3);
  k_gnn2<<<NBLKG, 512, 0, stream>>>(eidx, h3, ea1z, pW5, pW67,
                                    g2e_b1, b67, bnrep);
  k_head<<<(N_EDGES + 255) / 256, 256, 0, stream>>>(ea1z, bnrep, bn_g, bn_b,
                                                    fm_w2, fm_b2, out);
}

// Round 12
// 232.494 us; speedup vs baseline: 1.0996x; 1.0813x over previous
//
#include <hip/hip_runtime.h>

#define N_NODES 20000
#define N_EDGES 200000
#define HID 128
#define STR 136   // LDS row stride in u16: 272B rows -> every b128 access 16B-aligned
#define NBLK 3125 // 64-edge tiles
#define NREP 64   // BN accumulator replicas

typedef unsigned short u16;
using bf16x8 = __attribute__((ext_vector_type(8))) __bf16;
using f32x4  = __attribute__((ext_vector_type(4))) float;

__device__ __forceinline__ u16 f2bf(float f) {
  union { float f; unsigned u; } v; v.f = f;
  unsigned u = v.u;
  return (u16)((u + 0x7FFFu + ((u >> 16) & 1u)) >> 16);
}
__device__ __forceinline__ float bf2f(unsigned s) {
  union { unsigned u; float f; } v; v.u = s << 16;
  return v.f;
}
__device__ __forceinline__ bf16x8 ld8(const u16* p) { return *(const bf16x8*)p; }

__device__ __forceinline__ void zero_acc8(f32x4 acc[4]) {
#pragma unroll
  for (int i = 0; i < 4; ++i) acc[i] = (f32x4){0.f, 0.f, 0.f, 0.f};
}

// 8-wave wgemm: wave w owns output cols w*16..w*16+15 (ntile = wave).
template <int KSTEPS, typename AF>
__device__ __forceinline__ void wgemm8(const u16* __restrict__ PW, AF afrag,
                                       f32x4 acc[4], int lane, int wave) {
  const u16* pb = PW + (wave * 64 + lane) * 8;
  bf16x8 b[2];
  b[0] = ld8(pb);
#pragma unroll
  for (int ks = 0; ks < KSTEPS; ++ks) {
    const int cur = ks & 1;
    if (ks + 1 < KSTEPS) b[cur ^ 1] = ld8(pb + (ks + 1) * 4096);
#pragma unroll
    for (int mt = 0; mt < 4; ++mt) {
      bf16x8 a = afrag(ks, mt);
      acc[mt] = __builtin_amdgcn_mfma_f32_16x16x32_bf16(a, b[cur], acc[mt], 0, 0, 0);
    }
  }
}

// C/D: row(edge) = mt*16 + (lane>>4)*4 + r, col(ch) = wave*16 + (lane&15).
template <bool RELU>
__device__ __forceinline__ void epi_store8(u16* buf, const f32x4 acc[4],
                                           const float* __restrict__ bias,
                                           int lane, int wave) {
  const int c = lane & 15, q = lane >> 4;
  const float bb = bias[wave * 16 + c];
  const int col = wave * 16 + c;
#pragma unroll
  for (int mt = 0; mt < 4; ++mt)
#pragma unroll
    for (int r = 0; r < 4; ++r) {
      float v = acc[mt][r] + bb;
      if (RELU) v = fmaxf(v, 0.f);
      buf[(mt * 16 + q * 4 + r) * STR + col] = f2bf(v);
    }
}

__device__ __forceinline__ void flush_buf8(const u16* buf, u16* __restrict__ gout,
                                           int e0, int tid) {
#pragma unroll
  for (int it = 0; it < 2; ++it) {
    int cid = tid + it * 512, e = cid >> 4, p = cid & 15;
    uint4 v = *(const uint4*)(buf + e * STR + p * 8);
    *(uint4*)(gout + (size_t)(e0 + e) * HID + p * 8) = v;
  }
}

// 8-wave gather: 128 rows (64 B0 + 64 B1), 16 rows per wave, 16 lanes/row.
__device__ __forceinline__ void stage_gather8(const int* __restrict__ rowI,
                                              const int* __restrict__ colI,
                                              const u16* __restrict__ htab,
                                              u16* B0, u16* B1,
                                              int e0, int lane, int wave) {
  const int r = lane >> 4, p = lane & 15;
#pragma unroll
  for (int it = 0; it < 4; ++it) {
    int j = wave * 16 + it * 4 + r;  // 0..127
    int e = j & 63;
    int id = (j < 64) ? rowI[e0 + e] : colI[e0 + e];
    uint4 v = *(const uint4*)(htab + (size_t)id * HID + p * 8);
    *(uint4*)(((j < 64) ? B0 : B1) + e * STR + p * 8) = v;
  }
}

// ---- prep1: one block per output channel o. Folds encoder+fuse (Mt,C0,Wnt),
// b67, and W67 row o. Also zeroes bnrep (replaces the separate memset launch). ----
__global__ __launch_bounds__(128) void k_prep1(
    const float* __restrict__ emb, const float* __restrict__ conv_w,
    const float* __restrict__ conv_b, const float* __restrict__ fuse_w,
    const float* __restrict__ fuse_b,
    const float* __restrict__ fm_w1, const float* __restrict__ g2e_b2,
    const float* __restrict__ fm_b1, const float* __restrict__ w6,
    float* __restrict__ Mt, float* __restrict__ C0, float* __restrict__ Wnt,
    float* __restrict__ b67, float* __restrict__ W67, float* __restrict__ bnrep) {
  __shared__ float red[22][129];
  __shared__ float w7s[128];
  const int o = blockIdx.x;   // 0..127
  const int j = threadIdx.x;  // 0..127
  bnrep[o * 128 + j] = 0.f;   // 128 blk x 128 thr covers NREP*256 = 16384 floats
  float A[21];
  {
    float b0 = conv_b[j];
#pragma unroll
    for (int p = 0; p < 5; ++p) {
#pragma unroll
      for (int i = 0; i < 8; ++i) {
        float s = 0.f;
#pragma unroll
        for (int k = 0; k < 3; ++k) {
          int t = p + 1 - k;
          if (t >= 0 && t < 5) s += conv_w[(j * 8 + i) * 3 + k];
        }
        s *= 0.2f;
        if (i < 4) A[p * 4 + i] = s;
        else b0 += emb[p * 4 + (i - 4)] * s;
      }
    }
    A[20] = b0;
  }
  float w = fuse_w[o * 129 + j];   // coalesced across j
  float w7 = fm_w1[o * 128 + j];
  w7s[j] = w7;
#pragma unroll
  for (int qq = 0; qq < 21; ++qq) red[qq][j] = w * A[qq];
  red[21][j] = w7 * g2e_b2[j];
  __syncthreads();
  if (j < 22) {
    float s = 0.f;
    for (int t = 0; t < 128; ++t) s += red[j][t];
    if (j < 20)      Mt[j * 128 + o] = s;
    else if (j == 20) C0[o] = s + fuse_b[o];
    else              b67[o] = s + fm_b1[o];
  }
  if (j == 0) Wnt[o] = fuse_w[o * 129 + 128];
  float s = 0.f;
  for (int t = 0; t < 128; ++t) s += w7s[t] * w6[t * 128 + j];
  W67[o * 128 + j] = s;
}

// ---- prep2: blocks 0..40 pack weights; blocks 41.. encode nodes ----
struct PackArgs {
  const float* src[6];
  u16* dst[6];
  int Kin[6];
  int ksCum[7];
};

__global__ __launch_bounds__(256) void k_prep2(
    PackArgs pa, const float* __restrict__ x, const float* __restrict__ node_type,
    const float* __restrict__ Mt, const float* __restrict__ C0,
    const float* __restrict__ Wnt, u16* __restrict__ h2) {
  if (blockIdx.x < 41) {  // ---- pack branch ----
    int bk = blockIdx.x;
    int mi = 0;
    while (bk >= pa.ksCum[mi + 1]) ++mi;
    int ks = bk - pa.ksCum[mi];
    const float* W = pa.src[mi];
    u16* D = pa.dst[mi] + ks * 4096;
    int Kin = pa.Kin[mi];
#pragma unroll
    for (int t = 0; t < 16; ++t) {
      int el = t * 256 + (int)threadIdx.x;
      int j = el & 7, ln = (el >> 3) & 63, ntile = el >> 9;
      int k = ks * 32 + ((ln >> 4) << 3) + j;
      int n = ntile * 16 + (ln & 15);
      float v = (k < Kin) ? W[n * Kin + k] : 0.0f;
      D[el] = f2bf(v);
    }
    return;
  }
  // ---- encode branch: 16 nodes per block ----
  __shared__ float xs[16][20], nts[16], mts[20 * 128];
  const int tid = threadIdx.x;
  const int n0 = ((int)blockIdx.x - 41) * 16;
  for (int i = tid; i < 320; i += 256) xs[i / 20][i % 20] = x[n0 * 20 + i];
  if (tid < 16) nts[tid] = node_type[n0 + tid];
  for (int i = tid; i < 2560; i += 256) mts[i] = Mt[i];
  __syncthreads();
  const int nl = tid >> 4;
  const int c0 = (tid & 15) * 8;
  float nt = nts[nl];
  union { u16 s[8]; uint4 u; } o;
#pragma unroll
  for (int i = 0; i < 8; ++i) {
    int ch = c0 + i;
    float acc = C0[ch] + Wnt[ch] * nt;
#pragma unroll
    for (int qq = 0; qq < 20; ++qq) acc += xs[nl][qq] * mts[qq * 128 + ch];
    o.s[i] = f2bf(acc);
  }
  *(uint4*)(h2 + (size_t)(n0 + nl) * HID + c0) = o.u;
}

// ---- gnn1: 8 waves / 512 threads; wave w owns output cols w*16..w*16+15.
// Same LDS footprint (4 blocks/CU) -> 32 waves/CU = 100% occupancy target. ----
__global__ __launch_bounds__(512, 8) void k_gnn1(
    const int* __restrict__ eidx, const float* __restrict__ eattr,
    const u16* __restrict__ h2, const u16* __restrict__ pW1, const u16* __restrict__ pW2,
    const u16* __restrict__ pW3, const u16* __restrict__ pW4, const float* __restrict__ b1,
    const float* __restrict__ b2, const float* __restrict__ b3, const float* __restrict__ b4,
    u16* __restrict__ ea1, u16* __restrict__ h3) {
  __shared__ __align__(16) u16 B0[64 * STR], B1[64 * STR];
  const int tid = threadIdx.x, lane = tid & 63, wave = tid >> 6;
  const int e0 = blockIdx.x * 64;
  const int m = lane & 15, q = lane >> 4;
  const int aoff = m * STR + q * 8;
  const int* rowI = eidx;
  const int* colI = eidx + N_EDGES;

  stage_gather8(rowI, colI, h2, B0, B1, e0, lane, wave);

  bf16x8 ef[4];
#pragma unroll
  for (int mt = 0; mt < 4; ++mt) {
    union { u16 s[8]; uint4 u; bf16x8 v; } t;
    t.u = make_uint4(0u, 0u, 0u, 0u);
    if (q == 0) {
      float4 a = *(const float4*)(eattr + (size_t)(e0 + mt * 16 + m) * 4);
      t.s[0] = f2bf(a.x); t.s[1] = f2bf(a.y); t.s[2] = f2bf(a.z); t.s[3] = f2bf(a.w);
    }
    ef[mt] = t.v;
  }
  __syncthreads();  // S1

  f32x4 acc[4];
  zero_acc8(acc);  // GEMM1: K=288: [B0 h2r | B1 h2c | eattr-regs]
  wgemm8<9>(pW1, [&](int ks, int mt) -> bf16x8 {
    if (ks < 4) return ld8(B0 + aoff + mt * 16 * STR + ks * 32);
    if (ks < 8) return ld8(B1 + aoff + mt * 16 * STR + (ks - 4) * 32);
    return ef[mt];
  }, acc, lane, wave);
  __syncthreads();  // S2
  epi_store8<true>(B1, acc, b1, lane, wave);  // H -> B1
  __syncthreads();  // S3

  zero_acc8(acc);  // GEMM2: ea1 = W2 x H
  wgemm8<4>(pW2, [&](int ks, int mt) -> bf16x8 {
    return ld8(B1 + aoff + mt * 16 * STR + ks * 32);
  }, acc, lane, wave);
  epi_store8<false>(B0, acc, b2, lane, wave);  // ea1 -> B0
  __syncthreads();  // S4
  flush_buf8(B0, ea1, e0, tid);

  if (e0 < N_NODES) {
#pragma unroll
    for (int it = 0; it < 2; ++it) {
      int e = wave * 8 + it * 4 + q;
      int id = rowI[e0 + e];
      uint4 v = *(const uint4*)(h2 + (size_t)id * HID + m * 8);
      *(uint4*)(B1 + e * STR + m * 8) = v;
    }
    __syncthreads();  // S5

    zero_acc8(acc);  // GEMM3: K=256: [B1 h2row | B0 ea1]
    wgemm8<8>(pW3, [&](int ks, int mt) -> bf16x8 {
      if (ks < 4) return ld8(B1 + aoff + mt * 16 * STR + ks * 32);
      return ld8(B0 + aoff + mt * 16 * STR + (ks - 4) * 32);
    }, acc, lane, wave);
    __syncthreads();  // S6
    epi_store8<true>(B1, acc, b3, lane, wave);  // H' -> B1
    __syncthreads();  // S7

    zero_acc8(acc);  // GEMM4
    wgemm8<4>(pW4, [&](int ks, int mt) -> bf16x8 {
      return ld8(B1 + aoff + mt * 16 * STR + ks * 32);
    }, acc, lane, wave);
    epi_store8<false>(B0, acc, b4, lane, wave);  // h3 -> B0
    __syncthreads();  // S8
    flush_buf8(B0, h3, e0, tid);
  }
}

// ---- gnn2: 8 waves / 512 threads ----
__global__ __launch_bounds__(512, 8) void k_gnn2(
    const int* __restrict__ eidx, const u16* __restrict__ h3, u16* ea1z,
    const u16* __restrict__ pW5, const u16* __restrict__ pW67,
    const float* __restrict__ b5, const float* __restrict__ b67,
    float* __restrict__ bnrep) {
  __shared__ __align__(16) u16 B0[64 * STR], B1[64 * STR];
  const int tid = threadIdx.x, lane = tid & 63, wave = tid >> 6;
  const int e0 = blockIdx.x * 64;
  const int m = lane & 15, q = lane >> 4;
  const int aoff = m * STR + q * 8;
  const int* rowI = eidx;
  const int* colI = eidx + N_EDGES;

  stage_gather8(rowI, colI, h3, B0, B1, e0, lane, wave);
  __syncthreads();  // S1

  f32x4 acc[4];
  zero_acc8(acc);  // GEMM1a: ks 0..7 of K=384
  wgemm8<8>(pW5, [&](int ks, int mt) -> bf16x8 {
    if (ks < 4) return ld8(B0 + aoff + mt * 16 * STR + ks * 32);
    return ld8(B1 + aoff + mt * 16 * STR + (ks - 4) * 32);
  }, acc, lane, wave);
  __syncthreads();  // S2

#pragma unroll
  for (int it = 0; it < 2; ++it) {
    int cid = tid + it * 512, e = cid >> 4, p = cid & 15;
    uint4 v = *(const uint4*)(ea1z + (size_t)(e0 + e) * HID + p * 8);
    *(uint4*)(B0 + e * STR + p * 8) = v;
  }
  __syncthreads();  // S3

  wgemm8<4>(pW5 + 8 * 4096, [&](int ks, int mt) -> bf16x8 {
    return ld8(B0 + aoff + mt * 16 * STR + ks * 32);
  }, acc, lane, wave);
  epi_store8<true>(B1, acc, b5, lane, wave);  // H -> B1
  __syncthreads();  // S4

  zero_acc8(acc);  // GEMM2': z = W67 @ H + b67
  wgemm8<4>(pW67, [&](int ks, int mt) -> bf16x8 {
    return ld8(B1 + aoff + mt * 16 * STR + ks * 32);
  }, acc, lane, wave);

  {
    const int c = lane & 15;
    const int col = wave * 16 + c;
    const float bb = b67[col];
    float s0 = 0.f, q0 = 0.f;
#pragma unroll
    for (int mt = 0; mt < 4; ++mt)
#pragma unroll
      for (int r = 0; r < 4; ++r) {
        float v0 = acc[mt][r] + bb;
        s0 += v0; q0 += v0 * v0;
        int row = mt * 16 + q * 4 + r;
        B0[row * STR + col] = f2bf(v0);
      }
    s0 += __shfl_xor(s0, 16); s0 += __shfl_xor(s0, 32);
    q0 += __shfl_xor(q0, 16); q0 += __shfl_xor(q0, 32);
    if (lane < 16) {
      float* slot = bnrep + ((int)blockIdx.x & (NREP - 1)) * 256;
      atomicAdd(&slot[wave * 16 + lane], s0);
      atomicAdd(&slot[128 + wave * 16 + lane], q0);
    }
  }
  __syncthreads();  // S5
  flush_buf8(B0, ea1z, e0, tid);
}

// ---- head: cooperative (16 lanes per edge -> 16 lines/wave-instr, not 64);
// BN finalize from replica sum per block ----
__global__ __launch_bounds__(256) void k_head(const u16* __restrict__ z,
                                              const float* __restrict__ bnrep,
                                              const float* __restrict__ bn_g,
                                              const float* __restrict__ bn_b,
                                              const float* __restrict__ w2,
                                              const float* __restrict__ b2,
                                              float* __restrict__ out) {
  __shared__ float sh_s[128], sh_h[128], sh_w0[128], sh_w1[128], sh_w2[128];
  const int tid = threadIdx.x;
  {
    float s = 0.f;
    for (int r = 0; r < NREP; ++r) s += bnrep[r * 256 + tid];
    __shared__ float acc2[256];
    acc2[tid] = s;
    __syncthreads();
    if (tid < 128) {
      const float inv = 1.0f / (float)N_EDGES;
      float mu = acc2[tid] * inv;
      float var = acc2[128 + tid] * inv - mu * mu;
      float sc = bn_g[tid] * rsqrtf(var + 1e-5f);
      sh_s[tid] = sc;
      sh_h[tid] = bn_b[tid] - mu * sc;
      sh_w0[tid] = w2[tid];
      sh_w1[tid] = w2[128 + tid];
      sh_w2[tid] = w2[256 + tid];
    }
    __syncthreads();
  }
  const int lane = tid & 63, wave = tid >> 6;
  const int g = lane >> 4;       // edge-in-quad
  const int p = lane & 15;       // piece
  const int c0 = p * 8;
  const float bb0 = b2[0], bb1 = b2[1], bb2 = b2[2];
#pragma unroll 4
  for (int it = 0; it < 16; ++it) {
    int e = (int)blockIdx.x * 256 + wave * 64 + it * 4 + g;
    if (e >= N_EDGES) break;
    uint4 v = *(const uint4*)(z + (size_t)e * HID + c0);
    unsigned wv[4] = {v.x, v.y, v.z, v.w};
    float a0 = 0.f, a1 = 0.f, a2 = 0.f;
#pragma unroll
    for (int k = 0; k < 4; ++k) {
      int ch = c0 + k * 2;
      float lo = bf2f(wv[k] & 0xffffu), hi = bf2f(wv[k] >> 16);
      float r0 = fmaxf(fmaf(lo, sh_s[ch], sh_h[ch]), 0.f);
      float r1 = fmaxf(fmaf(hi, sh_s[ch + 1], sh_h[ch + 1]), 0.f);
      a0 += r0 * sh_w0[ch] + r1 * sh_w0[ch + 1];
      a1 += r0 * sh_w1[ch] + r1 * sh_w1[ch + 1];
      a2 += r0 * sh_w2[ch] + r1 * sh_w2[ch + 1];
    }
#pragma unroll
    for (int off = 1; off < 16; off <<= 1) {
      a0 += __shfl_xor(a0, off);
      a1 += __shfl_xor(a1, off);
      a2 += __shfl_xor(a2, off);
    }
    if (p < 3) out[e * 3 + p] = (p == 0) ? a0 + bb0 : (p == 1) ? a1 + bb1 : a2 + bb2;
  }
}

extern "C" void kernel_launch(void* const* d_in, const int* in_sizes, int n_in,
                              void* d_out, int out_size, void* d_ws, size_t ws_size,
                              hipStream_t stream) {
  const float* x         = (const float*)d_in[0];
  const int* eidx        = (const int*)d_in[1];
  const float* eattr     = (const float*)d_in[2];
  const float* node_type = (const float*)d_in[4];
  const float* emb       = (const float*)d_in[5];
  const float* conv_w    = (const float*)d_in[6];
  const float* conv_b    = (const float*)d_in[7];
  const float* fuse_w    = (const float*)d_in[8];
  const float* fuse_b    = (const float*)d_in[9];
  const float* g1e_w1    = (const float*)d_in[10];
  const float* g1e_b1    = (const float*)d_in[11];
  const float* g1e_w2    = (const float*)d_in[12];
  const float* g1e_b2    = (const float*)d_in[13];
  const float* g1n_w1    = (const float*)d_in[14];
  const float* g1n_b1    = (const float*)d_in[15];
  const float* g1n_w2    = (const float*)d_in[16];
  const float* g1n_b2    = (const float*)d_in[17];
  const float* g2e_w1    = (const float*)d_in[18];
  const float* g2e_b1    = (const float*)d_in[19];
  const float* g2e_w2    = (const float*)d_in[20];
  const float* g2e_b2    = (const float*)d_in[21];
  // d_in[22..25] = g2n_* : dead code in the reference (output unused)
  const float* fm_w1     = (const float*)d_in[26];
  const float* fm_b1     = (const float*)d_in[27];
  const float* bn_g      = (const float*)d_in[28];
  const float* bn_b      = (const float*)d_in[29];
  const float* fm_w2     = (const float*)d_in[30];
  const float* fm_b2     = (const float*)d_in[31];
  float* out = (float*)d_out;

  char* ws = (char*)d_ws;
  size_t off = 0;
  auto take = [&](size_t bytes) {
    void* p = ws + off;
    off = (off + bytes + 255) & ~(size_t)255;
    return p;
  };
  u16* h2   = (u16*)take((size_t)N_NODES * HID * 2);
  u16* h3   = (u16*)take((size_t)20032 * HID * 2);
  u16* ea1z = (u16*)take((size_t)N_EDGES * HID * 2);
  float* Mt    = (float*)take(20 * 128 * 4);
  float* C0    = (float*)take(128 * 4);
  float* Wnt   = (float*)take(128 * 4);
  float* b67   = (float*)take(128 * 4);
  float* W67f  = (float*)take(128 * 128 * 4);
  float* bnrep = (float*)take((size_t)NREP * 256 * 4);
  u16* pW1  = (u16*)take(9 * 4096 * 2);
  u16* pW2  = (u16*)take(4 * 4096 * 2);
  u16* pW3  = (u16*)take(8 * 4096 * 2);
  u16* pW4  = (u16*)take(4 * 4096 * 2);
  u16* pW5  = (u16*)take(12 * 4096 * 2);
  u16* pW67 = (u16*)take(4 * 4096 * 2);

  k_prep1<<<128, 128, 0, stream>>>(emb, conv_w, conv_b, fuse_w, fuse_b,
                                   fm_w1, g2e_b2, fm_b1, g2e_w2,
                                   Mt, C0, Wnt, b67, W67f, bnrep);

  PackArgs pa;
  const float* srcs[6] = {g1e_w1, g1e_w2, g1n_w1, g1n_w2, g2e_w1, W67f};
  u16* dsts[6] = {pW1, pW2, pW3, pW4, pW5, pW67};
  int kins[6] = {260, 128, 256, 128, 384, 128};
  int kst[6] = {9, 4, 8, 4, 12, 4};
  int cum = 0;
  for (int i = 0; i < 6; ++i) {
    pa.src[i] = srcs[i]; pa.dst[i] = dsts[i]; pa.Kin[i] = kins[i];
    pa.ksCum[i] = cum; cum += kst[i];
  }
  pa.ksCum[6] = cum;  // 41

  k_prep2<<<41 + N_NODES / 16, 256, 0, stream>>>(pa, x, node_type, Mt, C0, Wnt, h2);
  k_gnn1<<<NBLK, 512, 0, stream>>>(eidx, eattr, h2, pW1, pW2, pW3, pW4,
                                   g1e_b1, g1e_b2, g1n_b1, g1n_b2, ea1z, h3);
  k_gnn2<<<NBLK, 512, 0, stream>>>(eidx, h3, ea1z, pW5, pW67,
                                   g2e_b1, b67, bnrep);
  k_head<<<(N_EDGES + 255) / 256, 256, 0, stream>>>(ea1z, bnrep, bn_g, bn_b,
                                                    fm_w2, fm_b2, out);
}